// Round 2
// 614.991 us; speedup vs baseline: 1.1743x; 1.1743x over previous
//
#include <hip/hip_runtime.h>
#include <math.h>

#define B_  2
#define S_  2048
#define D_  1024
#define H_  16
#define L_  8
#define DH_ 64

typedef __attribute__((ext_vector_type(8))) short   short8;  // 8 bf16 (4 VGPRs)
typedef __attribute__((ext_vector_type(4))) float   f32x4;   // MFMA C/D frag
typedef __attribute__((ext_vector_type(8))) unsigned short us8;

static __device__ __forceinline__ unsigned short f2bf(float f) {
    union { float f; unsigned int u; } x; x.f = f;
    unsigned int r = x.u + 0x7FFFu + ((x.u >> 16) & 1u);   // RNE
    return (unsigned short)(r >> 16);
}
static __device__ __forceinline__ float bf2f(unsigned short u) {
    union { unsigned int u; float f; } x; x.u = ((unsigned int)u) << 16;
    return x.f;
}
static __device__ __forceinline__ void glds16(const void* g, void* l) {
    __builtin_amdgcn_global_load_lds(
        (const __attribute__((address_space(1))) void*)g,
        (__attribute__((address_space(3))) void*)l, 16, 0, 0);
}

// ---------------------------------------------------------------------------
// fp32 -> bf16 elementwise convert (n multiple of 8; grid = n/8/256)
// ---------------------------------------------------------------------------
__global__ __launch_bounds__(256) void cvt_bf16(const float* __restrict__ src,
                                                unsigned short* __restrict__ dst,
                                                long n)
{
    const long i = ((long)blockIdx.x * 256 + threadIdx.x) * 8;
    if (i >= n) return;
    const float4 v0 = *(const float4*)(src + i);
    const float4 v1 = *(const float4*)(src + i + 4);
    us8 o;
    o[0] = f2bf(v0.x); o[1] = f2bf(v0.y); o[2] = f2bf(v0.z); o[3] = f2bf(v0.w);
    o[4] = f2bf(v1.x); o[5] = f2bf(v1.y); o[6] = f2bf(v1.z); o[7] = f2bf(v1.w);
    *(us8*)(dst + i) = o;
}

// ---------------------------------------------------------------------------
// bf16 MFMA GEMM: C[m,n] = A[m,:] . Wt[n,:] + bias   (both K-contiguous)
// 128x128 tile, BK=32, 4 waves (2x2 of 64x64), 16x16x32 bf16 MFMA.
// mode 0: fp32 [M,N] out, bias0.
// mode 1: fused projection epilogue over N=5120 (Wqkv|Wk|Wv contiguous):
//   col <  3072 : bf16 qkv       -> out  (stride 3*D), bias0
//   col <  4096 : fp32 headsplit -> out2 seg 0 (k_col), bias1
//   col >= 4096 : fp32 headsplit -> out2 seg 1 (v_col), bias2
//   Region boundaries are 128-aligned, so branches are block-uniform.
// ---------------------------------------------------------------------------
__global__ __launch_bounds__(256) void gemm_bf16(
    const unsigned short* __restrict__ A,   // [M,K] bf16
    const unsigned short* __restrict__ Wt,  // [N,K] bf16
    const float* __restrict__ bias0,
    const float* __restrict__ bias1,
    const float* __restrict__ bias2,
    void* __restrict__ out,
    float* __restrict__ out2,
    int M, int N, int K, int mode)
{
    __shared__ __align__(16) unsigned short Asm[128 * 32];
    __shared__ __align__(16) unsigned short Bsm[128 * 32];

    const int t  = threadIdx.x;
    const int bm = blockIdx.y * 128;
    const int bn = blockIdx.x * 128;
    const int w = t >> 6, lane = t & 63;
    const int g = lane >> 4, c = lane & 15;
    const int wm = (w & 1) * 64, wn = (w >> 1) * 64;

    // staging: thread t -> slot t (issue 0) and slot 256+t (issue 1)
    const int r0  = t >> 2;                       // 0..63
    const int kc0 = (t & 3) ^ ((r0 >> 1) & 3);    // chunk swizzle
    const unsigned short* Ap0 = A  + (long)(bm + r0)      * K + kc0 * 8;
    const unsigned short* Ap1 = A  + (long)(bm + r0 + 64) * K + kc0 * 8;
    const unsigned short* Bp0 = Wt + (long)(bn + r0)      * K + kc0 * 8;
    const unsigned short* Bp1 = Wt + (long)(bn + r0 + 64) * K + kc0 * 8;
    unsigned short* AsD0 = Asm + t * 8;
    unsigned short* AsD1 = Asm + (256 + t) * 8;
    unsigned short* BsD0 = Bsm + t * 8;
    unsigned short* BsD1 = Bsm + (256 + t) * 8;

    // fragment LDS byte offsets
    const int xv = (c >> 1) & 3;
    int offA[4], offB[4];
#pragma unroll
    for (int i = 0; i < 4; i++) {
        offA[i] = (4 * (wm + i * 16 + c) + (g ^ xv)) * 16;
        offB[i] = (4 * (wn + i * 16 + c) + (g ^ xv)) * 16;
    }

    f32x4 acc[4][4];
#pragma unroll
    for (int i = 0; i < 4; i++)
#pragma unroll
        for (int j = 0; j < 4; j++) { acc[i][j][0]=0.f; acc[i][j][1]=0.f; acc[i][j][2]=0.f; acc[i][j][3]=0.f; }

    for (int k0 = 0; k0 < K; k0 += 32) {
        glds16(Ap0 + k0, AsD0);
        glds16(Ap1 + k0, AsD1);
        glds16(Bp0 + k0, BsD0);
        glds16(Bp1 + k0, BsD1);
        __syncthreads();                      // drains vmcnt -> LDS valid

        short8 af[4], bf[4];
#pragma unroll
        for (int i = 0; i < 4; i++) af[i] = *(const short8*)((const char*)Asm + offA[i]);
#pragma unroll
        for (int i = 0; i < 4; i++) bf[i] = *(const short8*)((const char*)Bsm + offB[i]);
#pragma unroll
        for (int mt = 0; mt < 4; mt++)
#pragma unroll
            for (int nt = 0; nt < 4; nt++)
                acc[mt][nt] = __builtin_amdgcn_mfma_f32_16x16x32_bf16(af[mt], bf[nt], acc[mt][nt], 0, 0, 0);
        __syncthreads();                      // protect LDS before next stage
    }

#pragma unroll
    for (int mt = 0; mt < 4; mt++) {
#pragma unroll
        for (int nt = 0; nt < 4; nt++) {
            const int col = bn + wn + nt * 16 + c;
            float bv;
            if (mode == 0)          bv = bias0[col];
            else if (col < 3 * D_)  bv = bias0[col];
            else if (col < 4 * D_)  bv = bias1[col - 3 * D_];
            else                    bv = bias2[col - 4 * D_];
            const int row0 = bm + wm + mt * 16 + g * 4;
#pragma unroll
            for (int reg = 0; reg < 4; reg++) {
                const float val = acc[mt][nt][reg] + bv;
                const int rr = row0 + reg;
                if (mode == 0) {
                    ((float*)out)[(long)rr * N + col] = val;
                } else if (col < 3 * D_) {
                    ((unsigned short*)out)[(long)rr * (3 * D_) + col] = f2bf(val);
                } else {
                    const int cc  = col - 3 * D_;
                    const int seg = cc >> 10;              // 0 = k_col, 1 = v_col
                    const int hh  = (cc >> 6) & 15;
                    const int d   = cc & 63;
                    const int b2 = rr >> 11, s2 = rr & 2047;
                    out2[(long)seg * ((long)B_ * H_ * S_ * DH_)
                         + (((long)(b2 * H_ + hh)) * S_ + s2) * DH_ + d] = val;
                }
            }
        }
    }
}

// ---------------------------------------------------------------------------
// Pre-pass (bf16 in): K -> packed [B,H,S,DH]; V -> transposed [B,H,DH,S].
// ---------------------------------------------------------------------------
__global__ __launch_bounds__(256) void prepass(const unsigned short* __restrict__ qkvb,
                                               unsigned short* __restrict__ Kb,
                                               unsigned short* __restrict__ Vtb)
{
    __shared__ __align__(16) unsigned short tile[64][72];
    const int bi = blockIdx.x;              // B*H*(S/64) = 1024
    const int st = bi & 31;
    const int bh = bi >> 5;
    const int b = bh >> 4, h = bh & 15;
    const int t = threadIdx.x;
    const int s_l = t >> 2;
    const int ch = (t & 3) * 16;            // 16 bf16 per thread

    const unsigned short* src = qkvb + (long)(b * S_ + st * 64 + s_l) * (3 * D_) + h * DH_;

    // K: straight copy into packed layout
    {
        us8 k0 = *(const us8*)(src + D_ + ch);
        us8 k1 = *(const us8*)(src + D_ + ch + 8);
        us8* kd = (us8*)(Kb + ((long)bh * S_ + st * 64 + s_l) * DH_ + ch);
        kd[0] = k0; kd[1] = k1;
    }
    // V: stage tile, transpose
    {
        us8 v0 = *(const us8*)(src + 2 * D_ + ch);
        us8 v1 = *(const us8*)(src + 2 * D_ + ch + 8);
        *(us8*)&tile[s_l][ch] = v0;
        *(us8*)&tile[s_l][ch + 8] = v1;
    }
    __syncthreads();
    {
        const int d_l = t >> 2;
        const int sch = (t & 3) * 16;
        us8 o0, o1;
#pragma unroll
        for (int i = 0; i < 8; i++) o0[i] = tile[sch + i][d_l];
#pragma unroll
        for (int i = 0; i < 8; i++) o1[i] = tile[sch + 8 + i][d_l];
        us8* dst = (us8*)(Vtb + ((long)bh * DH_ + d_l) * S_ + st * 64 + sch);
        dst[0] = o0; dst[1] = o1;
    }
}

// ---------------------------------------------------------------------------
// MFMA flash attention, latency-hiding restructure:
//  - 128-thread blocks, 2 fully independent 16-row waves (no barriers in loop;
//    P transpose through wave-private LDS slice fenced by s_waitcnt lgkmcnt(0))
//  - grid = B*H*(S/32) = 2048 blocks -> 8 blocks/CU, all resident
//    (__launch_bounds__(128,4) caps VGPR at 128; LDS 5.6 KB)
//  - bit-reversed qt ordering mixes long/short blocks across CUs
//  - V fragments loaded into registers before softmax (latency hidden)
//  - depth-memory (pk/pv fp32) merged at the END -> HBM traffic staggered
// ---------------------------------------------------------------------------
__global__ __launch_bounds__(128, 4) void attn_mfma(
    const unsigned short* __restrict__ qkvb,
    const unsigned short* __restrict__ Kb,
    const unsigned short* __restrict__ Vtb,
    const float* __restrict__ pk,
    const float* __restrict__ pv,
    unsigned short* __restrict__ ctxb)
{
    __shared__ float msc[2][16][8];
    __shared__ __align__(16) unsigned short Pl[2][16][72];

    const int bi  = blockIdx.x;
    const int bh  = bi & 31;
    const int idx = bi >> 5;                 // 0..63
    // bit-reverse 6 bits: any contiguous chunk of dispatched blocks gets a
    // spread of tile lengths -> balanced per-CU work sums
    const int qt  = ((idx & 1) << 5) | ((idx & 2) << 3) | ((idx & 4) << 1)
                  | ((idx & 8) >> 1) | ((idx & 16) >> 3) | ((idx & 32) >> 5);
    const int b = bh >> 4, h = bh & 15;
    const int w = threadIdx.x >> 6;          // 0..1, independent waves
    const int lane = threadIdx.x & 63;
    const int g = lane >> 4, c = lane & 15;
    const int qrow0 = qt * 32 + w * 16;
    const int dr    = qrow0 & 63;            // row offset inside diagonal tile
    const int tEnd  = qrow0 & ~63;
    const float scale = 0.125f;              // 1/sqrt(64); exact pow2

    // Q A-frags straight from bf16 qkv (scale applied post-MFMA)
    const unsigned short* qp = qkvb + ((long)(b * S_) + qrow0 + c) * (3 * D_) + h * DH_;
    const short8 qa0 = *(const short8*)(qp + g * 8);
    const short8 qa1 = *(const short8*)(qp + 32 + g * 8);

    float m[4], lsum[4];
    f32x4 O[4];
#pragma unroll
    for (int f = 0; f < 4; f++) { O[f][0]=0.f; O[f][1]=0.f; O[f][2]=0.f; O[f][3]=0.f; }
#pragma unroll
    for (int reg = 0; reg < 4; reg++) { m[reg] = -INFINITY; lsum[reg] = 0.0f; }

    const unsigned short* Kh = Kb + (long)bh * S_ * DH_;
    const unsigned short* Vh = Vtb + (long)bh * DH_ * S_;

    for (int t0 = 0; t0 <= tEnd; t0 += 64) {
        // ---- QK^T ----
        f32x4 sc[4];
#pragma unroll
        for (int nt = 0; nt < 4; nt++) {
            const unsigned short* kp = Kh + ((long)(t0 + nt * 16 + c)) * DH_ + g * 8;
            const short8 kb0 = *(const short8*)kp;
            const short8 kb1 = *(const short8*)(kp + 32);
            f32x4 a; a[0]=0.f; a[1]=0.f; a[2]=0.f; a[3]=0.f;
            a = __builtin_amdgcn_mfma_f32_16x16x32_bf16(qa0, kb0, a, 0, 0, 0);
            a = __builtin_amdgcn_mfma_f32_16x16x32_bf16(qa1, kb1, a, 0, 0, 0);
#pragma unroll
            for (int reg = 0; reg < 4; reg++) a[reg] *= scale;
            sc[nt] = a;
        }
        if (t0 == tEnd) {                   // diagonal tile: causal mask
#pragma unroll
            for (int nt = 0; nt < 4; nt++)
#pragma unroll
                for (int reg = 0; reg < 4; reg++)
                    sc[nt][reg] = (nt * 16 + c > dr + g * 4 + reg) ? -INFINITY : sc[nt][reg];
        }
        // ---- V fragments early: in flight under softmax + P round-trip ----
        short8 vb0[4], vb1[4];
#pragma unroll
        for (int nt = 0; nt < 4; nt++) {
            const unsigned short* vp = Vh + ((long)(nt * 16 + c)) * S_ + t0 + g * 8;
            vb0[nt] = *(const short8*)vp;
            vb1[nt] = *(const short8*)(vp + 32);
        }
        // ---- online softmax ----
        float al[4];
#pragma unroll
        for (int reg = 0; reg < 4; reg++) {
            float mx = fmaxf(fmaxf(sc[0][reg], sc[1][reg]), fmaxf(sc[2][reg], sc[3][reg]));
            mx = fmaxf(mx, __shfl_xor(mx, 1));
            mx = fmaxf(mx, __shfl_xor(mx, 2));
            mx = fmaxf(mx, __shfl_xor(mx, 4));
            mx = fmaxf(mx, __shfl_xor(mx, 8));
            const float mn = fmaxf(m[reg], mx);
            const float a  = __expf(m[reg] - mn);   // first tile: exp(-inf)=0
            m[reg] = mn; al[reg] = a;
            float ps = 0.0f;
#pragma unroll
            for (int nt = 0; nt < 4; nt++) {
                float p = __expf(sc[nt][reg] - mn);
                sc[nt][reg] = p; ps += p;
            }
            ps += __shfl_xor(ps, 1); ps += __shfl_xor(ps, 2);
            ps += __shfl_xor(ps, 4); ps += __shfl_xor(ps, 8);
            lsum[reg] = lsum[reg] * a + ps;
        }
#pragma unroll
        for (int f = 0; f < 4; f++)
#pragma unroll
            for (int reg = 0; reg < 4; reg++)
                O[f][reg] *= al[reg];
        // ---- P: C-layout -> wave-private LDS -> A-layout (no barrier) ----
#pragma unroll
        for (int nt = 0; nt < 4; nt++)
#pragma unroll
            for (int reg = 0; reg < 4; reg++)
                Pl[w][g * 4 + reg][nt * 16 + c] = f2bf(sc[nt][reg]);
        asm volatile("s_waitcnt lgkmcnt(0)" ::: "memory");
        const short8 pa0 = *(const short8*)&Pl[w][c][g * 8];
        const short8 pa1 = *(const short8*)&Pl[w][c][32 + g * 8];
        // ---- PV ----
#pragma unroll
        for (int nt = 0; nt < 4; nt++) {
            O[nt] = __builtin_amdgcn_mfma_f32_16x16x32_bf16(pa0, vb0[nt], O[nt], 0, 0, 0);
            O[nt] = __builtin_amdgcn_mfma_f32_16x16x32_bf16(pa1, vb1[nt], O[nt], 0, 0, 0);
        }
    }

    // ---- depth-memory merge (fp32 pk/pv) + epilogue ----
    {
        const int r0 = lane >> 3, l0 = lane & 7;
#pragma unroll
        for (int pass = 0; pass < 2; pass++) {
            const int r = r0 + pass * 8;
            const unsigned short* qr = qkvb + ((long)(b * S_) + qrow0 + r) * (3 * D_) + h * DH_;
            const float4* k4 = (const float4*)(pk + (((long)bh * S_ + qrow0 + r) * L_ + l0) * DH_);
            float d = 0.0f;
#pragma unroll
            for (int i = 0; i < 8; i++) {
                const us8 q8 = *(const us8*)(qr + i * 8);
                const float4 ka = k4[2 * i], kb2 = k4[2 * i + 1];
                d += bf2f(q8[0]) * ka.x  + bf2f(q8[1]) * ka.y
                   + bf2f(q8[2]) * ka.z  + bf2f(q8[3]) * ka.w
                   + bf2f(q8[4]) * kb2.x + bf2f(q8[5]) * kb2.y
                   + bf2f(q8[6]) * kb2.z + bf2f(q8[7]) * kb2.w;
            }
            msc[w][r][l0] = d * scale;
        }
    }
    asm volatile("s_waitcnt lgkmcnt(0)" ::: "memory");
#pragma unroll
    for (int reg = 0; reg < 4; reg++) {
        const int r = g * 4 + reg;
        float s8[8];
#pragma unroll
        for (int l = 0; l < 8; l++) s8[l] = msc[w][r][l];
        float mx = s8[0];
#pragma unroll
        for (int l = 1; l < 8; l++) mx = fmaxf(mx, s8[l]);
        const float mn = fmaxf(m[reg], mx);
        const float a  = __expf(m[reg] - mn);
        float p8[8]; float ls = 0.0f;
#pragma unroll
        for (int l = 0; l < 8; l++) { p8[l] = __expf(s8[l] - mn); ls += p8[l]; }
        const float rl = 1.0f / (lsum[reg] * a + ls);
        const float* pvr = pv + ((long)bh * S_ + qrow0 + r) * (L_ * DH_) + c;
        float acc4[4] = {0.f, 0.f, 0.f, 0.f};
#pragma unroll
        for (int l = 0; l < 8; l++)
#pragma unroll
            for (int f = 0; f < 4; f++)
                acc4[f] += p8[l] * pvr[l * DH_ + f * 16];
        unsigned short* op = ctxb + ((long)(b * S_) + qrow0 + r) * D_ + h * DH_ + c;
#pragma unroll
        for (int f = 0; f < 4; f++)
            op[f * 16] = f2bf((O[f][reg] * a + acc4[f]) * rl);
    }
}

// ---------------------------------------------------------------------------
extern "C" void kernel_launch(void* const* d_in, const int* in_sizes, int n_in,
                              void* d_out, int out_size, void* d_ws, size_t ws_size,
                              hipStream_t stream)
{
    const float* x    = (const float*)d_in[0];
    const float* pk   = (const float*)d_in[1];
    const float* pv   = (const float*)d_in[2];
    const float* Wqkv = (const float*)d_in[3];
    const float* bqkv = (const float*)d_in[4];
    const float* Wk   = (const float*)d_in[5];
    const float* bk   = (const float*)d_in[6];
    const float* Wv   = (const float*)d_in[7];
    const float* bv   = (const float*)d_in[8];
    const float* Wo   = (const float*)d_in[9];
    const float* bo   = (const float*)d_in[10];

    float* out   = (float*)d_out;                      // [B,S,D]
    float* k_col = out + (long)B_ * S_ * D_;           // [B,H,S,DH]
    // v_col = k_col + B*H*S*DH (seg 1 in fused gemm epilogue)

    const int M = B_ * S_;   // 4096
    const long MD = (long)M * D_;

    unsigned short* xb    = (unsigned short*)d_ws;     // [M,D]
    unsigned short* Wqkvb = xb + MD;                   // [3D,D]
    unsigned short* Wkb   = Wqkvb + 3L * D_ * D_;      // [D,D]  (contiguous after Wqkvb)
    unsigned short* Wvb   = Wkb + (long)D_ * D_;       // [D,D]  (contiguous after Wkb)
    unsigned short* Wob   = Wvb + (long)D_ * D_;
    unsigned short* qkvb  = Wob + (long)D_ * D_;       // [M,3D]
    unsigned short* Kb    = qkvb + 3 * MD;             // [B,H,S,DH]
    unsigned short* Vtb   = Kb + MD;                   // [B,H,DH,S]
    unsigned short* ctxb  = Vtb + MD;                  // [M,D]

    dim3 blk(256);

    // fp32 -> bf16 converts
    cvt_bf16<<<dim3((int)(MD / 2048)), blk, 0, stream>>>(x, xb, MD);
    cvt_bf16<<<dim3((int)(3L * D_ * D_ / 2048)), blk, 0, stream>>>(Wqkv, Wqkvb, 3L * D_ * D_);
    cvt_bf16<<<dim3((int)((long)D_ * D_ / 2048)), blk, 0, stream>>>(Wk, Wkb, (long)D_ * D_);
    cvt_bf16<<<dim3((int)((long)D_ * D_ / 2048)), blk, 0, stream>>>(Wv, Wvb, (long)D_ * D_);
    cvt_bf16<<<dim3((int)((long)D_ * D_ / 2048)), blk, 0, stream>>>(Wo, Wob, (long)D_ * D_);

    // 1) fused projections: qkv (bf16) + k_col/v_col (fp32 head-split)
    //    Wqkvb|Wkb|Wvb contiguous -> one [M,5120] GEMM, 1280 blocks
    gemm_bf16<<<dim3(5 * D_ / 128, M / 128), blk, 0, stream>>>(
        xb, Wqkvb, bqkv, bk, bv, qkvb, k_col, M, 5 * D_, D_, 1);
    // 2) packed bf16 K + transposed bf16 V
    prepass<<<dim3(B_ * H_ * (S_ / 64)), blk, 0, stream>>>(qkvb, Kb, Vtb);
    // 3) attention -> bf16 ctx (2048 blocks x 128 threads, all resident)
    attn_mfma<<<dim3(B_ * H_ * (S_ / 32)), dim3(128), 0, stream>>>(qkvb, Kb, Vtb, pk, pv, ctxb);
    // 4) out = ctx @ Wo.T + bo -> fp32
    gemm_bf16<<<dim3(D_ / 128, M / 128), blk, 0, stream>>>(
        ctxb, Wob, bo, nullptr, nullptr, out, nullptr, M, D_, D_, 0);
}

// Round 3
// 567.164 us; speedup vs baseline: 1.2733x; 1.0843x over previous
//
#include <hip/hip_runtime.h>
#include <math.h>

#define B_  2
#define S_  2048
#define D_  1024
#define H_  16
#define L_  8
#define DH_ 64

typedef __attribute__((ext_vector_type(8))) short   short8;  // 8 bf16 (4 VGPRs)
typedef __attribute__((ext_vector_type(4))) float   f32x4;   // MFMA C/D frag
typedef __attribute__((ext_vector_type(8))) unsigned short us8;

static __device__ __forceinline__ unsigned short f2bf(float f) {
    union { float f; unsigned int u; } x; x.f = f;
    unsigned int r = x.u + 0x7FFFu + ((x.u >> 16) & 1u);   // RNE
    return (unsigned short)(r >> 16);
}
static __device__ __forceinline__ float bf2f(unsigned short u) {
    union { unsigned int u; float f; } x; x.u = ((unsigned int)u) << 16;
    return x.f;
}
static __device__ __forceinline__ void glds16(const void* g, void* l) {
    __builtin_amdgcn_global_load_lds(
        (const __attribute__((address_space(1))) void*)g,
        (__attribute__((address_space(3))) void*)l, 16, 0, 0);
}

// ---------------------------------------------------------------------------
// fp32 -> bf16 elementwise convert (n multiple of 8; grid = n/8/256)
// ---------------------------------------------------------------------------
__global__ __launch_bounds__(256) void cvt_bf16(const float* __restrict__ src,
                                                unsigned short* __restrict__ dst,
                                                long n)
{
    const long i = ((long)blockIdx.x * 256 + threadIdx.x) * 8;
    if (i >= n) return;
    const float4 v0 = *(const float4*)(src + i);
    const float4 v1 = *(const float4*)(src + i + 4);
    us8 o;
    o[0] = f2bf(v0.x); o[1] = f2bf(v0.y); o[2] = f2bf(v0.z); o[3] = f2bf(v0.w);
    o[4] = f2bf(v1.x); o[5] = f2bf(v1.y); o[6] = f2bf(v1.z); o[7] = f2bf(v1.w);
    *(us8*)(dst + i) = o;
}

// ---------------------------------------------------------------------------
// bf16 MFMA GEMM: C[m,n] = A[m,:] . Wt[n,:] + bias   (both K-contiguous)
// 128x128 tile, BK=32, 4 waves (2x2 of 64x64), 16x16x32 bf16 MFMA.
// mode 0: fp32 [M,N] out, bias0.
// mode 1: fused projection epilogue over N=5120 (Wqkv|Wk|Wv contiguous):
//   col <  3072 : bf16 qkv       -> out  (stride 3*D), bias0
//   col <  4096 : fp32 headsplit -> out2 seg 0 (k_col), bias1
//   col >= 4096 : fp32 headsplit -> out2 seg 1 (v_col), bias2
//   Region boundaries are 128-aligned, so branches are block-uniform.
// ---------------------------------------------------------------------------
__global__ __launch_bounds__(256) void gemm_bf16(
    const unsigned short* __restrict__ A,   // [M,K] bf16
    const unsigned short* __restrict__ Wt,  // [N,K] bf16
    const float* __restrict__ bias0,
    const float* __restrict__ bias1,
    const float* __restrict__ bias2,
    void* __restrict__ out,
    float* __restrict__ out2,
    int M, int N, int K, int mode)
{
    __shared__ __align__(16) unsigned short Asm[128 * 32];
    __shared__ __align__(16) unsigned short Bsm[128 * 32];

    const int t  = threadIdx.x;
    const int bm = blockIdx.y * 128;
    const int bn = blockIdx.x * 128;
    const int w = t >> 6, lane = t & 63;
    const int g = lane >> 4, c = lane & 15;
    const int wm = (w & 1) * 64, wn = (w >> 1) * 64;

    // staging: thread t -> slot t (issue 0) and slot 256+t (issue 1)
    const int r0  = t >> 2;                       // 0..63
    const int kc0 = (t & 3) ^ ((r0 >> 1) & 3);    // chunk swizzle
    const unsigned short* Ap0 = A  + (long)(bm + r0)      * K + kc0 * 8;
    const unsigned short* Ap1 = A  + (long)(bm + r0 + 64) * K + kc0 * 8;
    const unsigned short* Bp0 = Wt + (long)(bn + r0)      * K + kc0 * 8;
    const unsigned short* Bp1 = Wt + (long)(bn + r0 + 64) * K + kc0 * 8;
    unsigned short* AsD0 = Asm + t * 8;
    unsigned short* AsD1 = Asm + (256 + t) * 8;
    unsigned short* BsD0 = Bsm + t * 8;
    unsigned short* BsD1 = Bsm + (256 + t) * 8;

    // fragment LDS byte offsets
    const int xv = (c >> 1) & 3;
    int offA[4], offB[4];
#pragma unroll
    for (int i = 0; i < 4; i++) {
        offA[i] = (4 * (wm + i * 16 + c) + (g ^ xv)) * 16;
        offB[i] = (4 * (wn + i * 16 + c) + (g ^ xv)) * 16;
    }

    f32x4 acc[4][4];
#pragma unroll
    for (int i = 0; i < 4; i++)
#pragma unroll
        for (int j = 0; j < 4; j++) { acc[i][j][0]=0.f; acc[i][j][1]=0.f; acc[i][j][2]=0.f; acc[i][j][3]=0.f; }

    for (int k0 = 0; k0 < K; k0 += 32) {
        glds16(Ap0 + k0, AsD0);
        glds16(Ap1 + k0, AsD1);
        glds16(Bp0 + k0, BsD0);
        glds16(Bp1 + k0, BsD1);
        __syncthreads();                      // drains vmcnt -> LDS valid

        short8 af[4], bf[4];
#pragma unroll
        for (int i = 0; i < 4; i++) af[i] = *(const short8*)((const char*)Asm + offA[i]);
#pragma unroll
        for (int i = 0; i < 4; i++) bf[i] = *(const short8*)((const char*)Bsm + offB[i]);
#pragma unroll
        for (int mt = 0; mt < 4; mt++)
#pragma unroll
            for (int nt = 0; nt < 4; nt++)
                acc[mt][nt] = __builtin_amdgcn_mfma_f32_16x16x32_bf16(af[mt], bf[nt], acc[mt][nt], 0, 0, 0);
        __syncthreads();                      // protect LDS before next stage
    }

#pragma unroll
    for (int mt = 0; mt < 4; mt++) {
#pragma unroll
        for (int nt = 0; nt < 4; nt++) {
            const int col = bn + wn + nt * 16 + c;
            float bv;
            if (mode == 0)          bv = bias0[col];
            else if (col < 3 * D_)  bv = bias0[col];
            else if (col < 4 * D_)  bv = bias1[col - 3 * D_];
            else                    bv = bias2[col - 4 * D_];
            const int row0 = bm + wm + mt * 16 + g * 4;
#pragma unroll
            for (int reg = 0; reg < 4; reg++) {
                const float val = acc[mt][nt][reg] + bv;
                const int rr = row0 + reg;
                if (mode == 0) {
                    ((float*)out)[(long)rr * N + col] = val;
                } else if (col < 3 * D_) {
                    ((unsigned short*)out)[(long)rr * (3 * D_) + col] = f2bf(val);
                } else {
                    const int cc  = col - 3 * D_;
                    const int seg = cc >> 10;              // 0 = k_col, 1 = v_col
                    const int hh  = (cc >> 6) & 15;
                    const int d   = cc & 63;
                    const int b2 = rr >> 11, s2 = rr & 2047;
                    out2[(long)seg * ((long)B_ * H_ * S_ * DH_)
                         + (((long)(b2 * H_ + hh)) * S_ + s2) * DH_ + d] = val;
                }
            }
        }
    }
}

// ---------------------------------------------------------------------------
// Pre-pass (bf16 in): K -> packed [B,H,S,DH]; V -> transposed [B,H,DH,S].
// ---------------------------------------------------------------------------
__global__ __launch_bounds__(256) void prepass(const unsigned short* __restrict__ qkvb,
                                               unsigned short* __restrict__ Kb,
                                               unsigned short* __restrict__ Vtb)
{
    __shared__ __align__(16) unsigned short tile[64][72];
    const int bi = blockIdx.x;              // B*H*(S/64) = 1024
    const int st = bi & 31;
    const int bh = bi >> 5;
    const int b = bh >> 4, h = bh & 15;
    const int t = threadIdx.x;
    const int s_l = t >> 2;
    const int ch = (t & 3) * 16;            // 16 bf16 per thread

    const unsigned short* src = qkvb + (long)(b * S_ + st * 64 + s_l) * (3 * D_) + h * DH_;

    // K: straight copy into packed layout
    {
        us8 k0 = *(const us8*)(src + D_ + ch);
        us8 k1 = *(const us8*)(src + D_ + ch + 8);
        us8* kd = (us8*)(Kb + ((long)bh * S_ + st * 64 + s_l) * DH_ + ch);
        kd[0] = k0; kd[1] = k1;
    }
    // V: stage tile, transpose
    {
        us8 v0 = *(const us8*)(src + 2 * D_ + ch);
        us8 v1 = *(const us8*)(src + 2 * D_ + ch + 8);
        *(us8*)&tile[s_l][ch] = v0;
        *(us8*)&tile[s_l][ch + 8] = v1;
    }
    __syncthreads();
    {
        const int d_l = t >> 2;
        const int sch = (t & 3) * 16;
        us8 o0, o1;
#pragma unroll
        for (int i = 0; i < 8; i++) o0[i] = tile[sch + i][d_l];
#pragma unroll
        for (int i = 0; i < 8; i++) o1[i] = tile[sch + 8 + i][d_l];
        us8* dst = (us8*)(Vtb + ((long)bh * DH_ + d_l) * S_ + st * 64 + sch);
        dst[0] = o0; dst[1] = o1;
    }
}

// ---------------------------------------------------------------------------
// MFMA flash attention, round 3: register-pipelined.
//  - K register double-buffer: K[t+1] loaded into the alternate named register
//    set BEFORE tile t's compute (2x-unrolled loop, static indexing) -> K load
//    latency hides under a full tile of compute.
//  - V loaded at top of its own tile body; __launch_bounds__(128,2) gives a
//    256-VGPR budget so vv stays live across softmax (round 2 had VGPR=64 and
//    sank V loads to the PV point -> serial latency, the round-2 bottleneck).
//  - softmax: per-lane lsum accumulation (one cross-lane reduce at the END,
//    -4 shfl/reg/iter) + defer-max THR=8 (skip cross-lane max + O rescale
//    when __all(lane_max <= m+8); exact math, p <= e^8).
//  - no barriers in loop; wave-private LDS P-transpose fenced by lgkmcnt(0).
// ---------------------------------------------------------------------------
#define LOAD_KTILE(K0, K1, TT) do {                                         \
    _Pragma("unroll")                                                       \
    for (int nt_ = 0; nt_ < 4; nt_++) {                                     \
        const unsigned short* kp_ = Kh + ((long)((TT) + nt_ * 16 + c)) * DH_ + g * 8; \
        K0[nt_] = *(const short8*)kp_;                                      \
        K1[nt_] = *(const short8*)(kp_ + 32);                               \
    }                                                                       \
} while (0)

#define ATTN_TILE(TT, K0, K1) do {                                          \
    const int t0_ = (TT);                                                   \
    short8 vv0_[4], vv1_[4];                                                \
    _Pragma("unroll")                                                       \
    for (int nt_ = 0; nt_ < 4; nt_++) {                                     \
        const unsigned short* vp_ = Vh + ((long)(nt_ * 16 + c)) * S_ + t0_ + g * 8; \
        vv0_[nt_] = *(const short8*)vp_;                                    \
        vv1_[nt_] = *(const short8*)(vp_ + 32);                             \
    }                                                                       \
    f32x4 sc_[4];                                                           \
    _Pragma("unroll")                                                       \
    for (int nt_ = 0; nt_ < 4; nt_++) {                                     \
        f32x4 a_; a_[0]=0.f; a_[1]=0.f; a_[2]=0.f; a_[3]=0.f;               \
        a_ = __builtin_amdgcn_mfma_f32_16x16x32_bf16(qa0, K0[nt_], a_, 0, 0, 0); \
        a_ = __builtin_amdgcn_mfma_f32_16x16x32_bf16(qa1, K1[nt_], a_, 0, 0, 0); \
        _Pragma("unroll")                                                   \
        for (int r_ = 0; r_ < 4; r_++) a_[r_] *= scale;                     \
        sc_[nt_] = a_;                                                      \
    }                                                                       \
    if (t0_ == tEnd) {                                                      \
        _Pragma("unroll")                                                   \
        for (int nt_ = 0; nt_ < 4; nt_++)                                   \
            _Pragma("unroll")                                               \
            for (int r_ = 0; r_ < 4; r_++)                                  \
                sc_[nt_][r_] = (nt_ * 16 + c > dr + g * 4 + r_) ? -INFINITY : sc_[nt_][r_]; \
    }                                                                       \
    float al_[4]; bool resc_ = false;                                       \
    _Pragma("unroll")                                                       \
    for (int r_ = 0; r_ < 4; r_++) {                                        \
        const float mx_ = fmaxf(fmaxf(sc_[0][r_], sc_[1][r_]),              \
                                fmaxf(sc_[2][r_], sc_[3][r_]));             \
        if (__all(mx_ <= m[r_] + 8.0f)) {                                   \
            al_[r_] = 1.0f;                                                 \
            float ps_ = 0.0f;                                               \
            _Pragma("unroll")                                               \
            for (int nt_ = 0; nt_ < 4; nt_++) {                             \
                const float p_ = __expf(sc_[nt_][r_] - m[r_]);              \
                sc_[nt_][r_] = p_; ps_ += p_;                               \
            }                                                               \
            lsum_l[r_] += ps_;                                              \
        } else {                                                            \
            resc_ = true;                                                   \
            float M_ = mx_;                                                 \
            M_ = fmaxf(M_, __shfl_xor(M_, 1));                              \
            M_ = fmaxf(M_, __shfl_xor(M_, 2));                              \
            M_ = fmaxf(M_, __shfl_xor(M_, 4));                              \
            M_ = fmaxf(M_, __shfl_xor(M_, 8));                              \
            const float mn_ = fmaxf(m[r_], M_);                             \
            const float a_ = __expf(m[r_] - mn_);                           \
            m[r_] = mn_; al_[r_] = a_;                                      \
            float ps_ = 0.0f;                                               \
            _Pragma("unroll")                                               \
            for (int nt_ = 0; nt_ < 4; nt_++) {                             \
                const float p_ = __expf(sc_[nt_][r_] - mn_);                \
                sc_[nt_][r_] = p_; ps_ += p_;                               \
            }                                                               \
            lsum_l[r_] = lsum_l[r_] * a_ + ps_;                             \
        }                                                                   \
    }                                                                       \
    if (resc_) {                                                            \
        _Pragma("unroll")                                                   \
        for (int f_ = 0; f_ < 4; f_++)                                      \
            _Pragma("unroll")                                               \
            for (int r_ = 0; r_ < 4; r_++)                                  \
                O[f_][r_] *= al_[r_];                                       \
    }                                                                       \
    _Pragma("unroll")                                                       \
    for (int nt_ = 0; nt_ < 4; nt_++)                                       \
        _Pragma("unroll")                                                   \
        for (int r_ = 0; r_ < 4; r_++)                                      \
            Pl[w][g * 4 + r_][nt_ * 16 + c] = f2bf(sc_[nt_][r_]);           \
    asm volatile("s_waitcnt lgkmcnt(0)" ::: "memory");                      \
    const short8 pa0_ = *(const short8*)&Pl[w][c][g * 8];                   \
    const short8 pa1_ = *(const short8*)&Pl[w][c][32 + g * 8];              \
    _Pragma("unroll")                                                       \
    for (int nt_ = 0; nt_ < 4; nt_++) {                                     \
        O[nt_] = __builtin_amdgcn_mfma_f32_16x16x32_bf16(pa0_, vv0_[nt_], O[nt_], 0, 0, 0); \
        O[nt_] = __builtin_amdgcn_mfma_f32_16x16x32_bf16(pa1_, vv1_[nt_], O[nt_], 0, 0, 0); \
    }                                                                       \
} while (0)

__global__ __launch_bounds__(128, 2) void attn_mfma(
    const unsigned short* __restrict__ qkvb,
    const unsigned short* __restrict__ Kb,
    const unsigned short* __restrict__ Vtb,
    const float* __restrict__ pk,
    const float* __restrict__ pv,
    unsigned short* __restrict__ ctxb)
{
    __shared__ float msc[2][16][8];
    __shared__ __align__(16) unsigned short Pl[2][16][72];

    const int bi  = blockIdx.x;
    const int bh  = bi & 31;
    const int idx = bi >> 5;                 // 0..63
    // bit-reverse 6 bits: any contiguous chunk of dispatched blocks gets a
    // spread of tile lengths -> balanced per-CU work sums
    const int qt  = ((idx & 1) << 5) | ((idx & 2) << 3) | ((idx & 4) << 1)
                  | ((idx & 8) >> 1) | ((idx & 16) >> 3) | ((idx & 32) >> 5);
    const int b = bh >> 4, h = bh & 15;
    const int w = threadIdx.x >> 6;          // 0..1, independent waves
    const int lane = threadIdx.x & 63;
    const int g = lane >> 4, c = lane & 15;
    const int qrow0 = qt * 32 + w * 16;
    const int dr    = qrow0 & 63;            // row offset inside diagonal tile
    const int tEnd  = qrow0 & ~63;
    const float scale = 0.125f;              // 1/sqrt(64); exact pow2

    // Q A-frags straight from bf16 qkv (scale applied post-MFMA)
    const unsigned short* qp = qkvb + ((long)(b * S_) + qrow0 + c) * (3 * D_) + h * DH_;
    const short8 qa0 = *(const short8*)(qp + g * 8);
    const short8 qa1 = *(const short8*)(qp + 32 + g * 8);

    float m[4], lsum_l[4];
    f32x4 O[4];
#pragma unroll
    for (int f = 0; f < 4; f++) { O[f][0]=0.f; O[f][1]=0.f; O[f][2]=0.f; O[f][3]=0.f; }
#pragma unroll
    for (int reg = 0; reg < 4; reg++) { m[reg] = -INFINITY; lsum_l[reg] = 0.0f; }

    const unsigned short* Kh = Kb + (long)bh * S_ * DH_;
    const unsigned short* Vh = Vtb + (long)bh * DH_ * S_;

    // register-pipelined main loop (K double-buffer, 2 tiles per trip)
    short8 kA0[4], kA1[4], kB0[4], kB1[4];
    LOAD_KTILE(kA0, kA1, 0);
    int t0 = 0;
    for (;;) {
        if (t0 + 64 <= tEnd) LOAD_KTILE(kB0, kB1, t0 + 64);
        ATTN_TILE(t0, kA0, kA1);
        if (t0 == tEnd) break;
        t0 += 64;
        if (t0 + 64 <= tEnd) LOAD_KTILE(kA0, kA1, t0 + 64);
        ATTN_TILE(t0, kB0, kB1);
        if (t0 == tEnd) break;
        t0 += 64;
    }

    // cross-lane lsum reduce (deferred from the main loop)
    float lsum[4];
#pragma unroll
    for (int reg = 0; reg < 4; reg++) {
        float s = lsum_l[reg];
        s += __shfl_xor(s, 1); s += __shfl_xor(s, 2);
        s += __shfl_xor(s, 4); s += __shfl_xor(s, 8);
        lsum[reg] = s;
    }

    // ---- depth-memory merge (fp32 pk/pv) + epilogue ----
    {
        const int r0 = lane >> 3, l0 = lane & 7;
#pragma unroll
        for (int pass = 0; pass < 2; pass++) {
            const int r = r0 + pass * 8;
            const unsigned short* qr = qkvb + ((long)(b * S_) + qrow0 + r) * (3 * D_) + h * DH_;
            const float4* k4 = (const float4*)(pk + (((long)bh * S_ + qrow0 + r) * L_ + l0) * DH_);
            float d = 0.0f;
#pragma unroll
            for (int i = 0; i < 8; i++) {
                const us8 q8 = *(const us8*)(qr + i * 8);
                const float4 ka = k4[2 * i], kb2 = k4[2 * i + 1];
                d += bf2f(q8[0]) * ka.x  + bf2f(q8[1]) * ka.y
                   + bf2f(q8[2]) * ka.z  + bf2f(q8[3]) * ka.w
                   + bf2f(q8[4]) * kb2.x + bf2f(q8[5]) * kb2.y
                   + bf2f(q8[6]) * kb2.z + bf2f(q8[7]) * kb2.w;
            }
            msc[w][r][l0] = d * scale;
        }
    }
    asm volatile("s_waitcnt lgkmcnt(0)" ::: "memory");
#pragma unroll
    for (int reg = 0; reg < 4; reg++) {
        const int r = g * 4 + reg;
        float s8[8];
#pragma unroll
        for (int l = 0; l < 8; l++) s8[l] = msc[w][r][l];
        float mx = s8[0];
#pragma unroll
        for (int l = 1; l < 8; l++) mx = fmaxf(mx, s8[l]);
        const float mn = fmaxf(m[reg], mx);
        const float a  = __expf(m[reg] - mn);
        float p8[8]; float ls = 0.0f;
#pragma unroll
        for (int l = 0; l < 8; l++) { p8[l] = __expf(s8[l] - mn); ls += p8[l]; }
        const float rl = 1.0f / (lsum[reg] * a + ls);
        const float* pvr = pv + ((long)bh * S_ + qrow0 + r) * (L_ * DH_) + c;
        float acc4[4] = {0.f, 0.f, 0.f, 0.f};
#pragma unroll
        for (int l = 0; l < 8; l++)
#pragma unroll
            for (int f = 0; f < 4; f++)
                acc4[f] += p8[l] * pvr[l * DH_ + f * 16];
        unsigned short* op = ctxb + ((long)(b * S_) + qrow0 + r) * D_ + h * DH_ + c;
#pragma unroll
        for (int f = 0; f < 4; f++)
            op[f * 16] = f2bf((O[f][reg] * a + acc4[f]) * rl);
    }
}

// ---------------------------------------------------------------------------
extern "C" void kernel_launch(void* const* d_in, const int* in_sizes, int n_in,
                              void* d_out, int out_size, void* d_ws, size_t ws_size,
                              hipStream_t stream)
{
    const float* x    = (const float*)d_in[0];
    const float* pk   = (const float*)d_in[1];
    const float* pv   = (const float*)d_in[2];
    const float* Wqkv = (const float*)d_in[3];
    const float* bqkv = (const float*)d_in[4];
    const float* Wk   = (const float*)d_in[5];
    const float* bk   = (const float*)d_in[6];
    const float* Wv   = (const float*)d_in[7];
    const float* bv   = (const float*)d_in[8];
    const float* Wo   = (const float*)d_in[9];
    const float* bo   = (const float*)d_in[10];

    float* out   = (float*)d_out;                      // [B,S,D]
    float* k_col = out + (long)B_ * S_ * D_;           // [B,H,S,DH]
    // v_col = k_col + B*H*S*DH (seg 1 in fused gemm epilogue)

    const int M = B_ * S_;   // 4096
    const long MD = (long)M * D_;

    unsigned short* xb    = (unsigned short*)d_ws;     // [M,D]
    unsigned short* Wqkvb = xb + MD;                   // [3D,D]
    unsigned short* Wkb   = Wqkvb + 3L * D_ * D_;      // [D,D]  (contiguous after Wqkvb)
    unsigned short* Wvb   = Wkb + (long)D_ * D_;       // [D,D]  (contiguous after Wkb)
    unsigned short* Wob   = Wvb + (long)D_ * D_;
    unsigned short* qkvb  = Wob + (long)D_ * D_;       // [M,3D]
    unsigned short* Kb    = qkvb + 3 * MD;             // [B,H,S,DH]
    unsigned short* Vtb   = Kb + MD;                   // [B,H,DH,S]
    unsigned short* ctxb  = Vtb + MD;                  // [M,D]

    dim3 blk(256);

    // fp32 -> bf16 converts
    cvt_bf16<<<dim3((int)(MD / 2048)), blk, 0, stream>>>(x, xb, MD);
    cvt_bf16<<<dim3((int)(3L * D_ * D_ / 2048)), blk, 0, stream>>>(Wqkv, Wqkvb, 3L * D_ * D_);
    cvt_bf16<<<dim3((int)((long)D_ * D_ / 2048)), blk, 0, stream>>>(Wk, Wkb, (long)D_ * D_);
    cvt_bf16<<<dim3((int)((long)D_ * D_ / 2048)), blk, 0, stream>>>(Wv, Wvb, (long)D_ * D_);
    cvt_bf16<<<dim3((int)((long)D_ * D_ / 2048)), blk, 0, stream>>>(Wo, Wob, (long)D_ * D_);

    // 1) fused projections: qkv (bf16) + k_col/v_col (fp32 head-split)
    //    Wqkvb|Wkb|Wvb contiguous -> one [M,5120] GEMM, 1280 blocks
    gemm_bf16<<<dim3(5 * D_ / 128, M / 128), blk, 0, stream>>>(
        xb, Wqkvb, bqkv, bk, bv, qkvb, k_col, M, 5 * D_, D_, 1);
    // 2) packed bf16 K + transposed bf16 V
    prepass<<<dim3(B_ * H_ * (S_ / 64)), blk, 0, stream>>>(qkvb, Kb, Vtb);
    // 3) attention -> bf16 ctx (2048 blocks x 128 threads)
    attn_mfma<<<dim3(B_ * H_ * (S_ / 32)), dim3(128), 0, stream>>>(qkvb, Kb, Vtb, pk, pv, ctxb);
    // 4) out = ctx @ Wo.T + bo -> fp32
    gemm_bf16<<<dim3(D_ / 128, M / 128), blk, 0, stream>>>(
        ctxb, Wob, bo, nullptr, nullptr, out, nullptr, M, D_, D_, 0);
}

// Round 4
// 542.223 us; speedup vs baseline: 1.3319x; 1.0460x over previous
//
#include <hip/hip_runtime.h>
#include <math.h>

#define B_  2
#define S_  2048
#define D_  1024
#define H_  16
#define L_  8
#define DH_ 64

typedef __attribute__((ext_vector_type(8))) short   short8;  // 8 bf16 (4 VGPRs)
typedef __attribute__((ext_vector_type(4))) float   f32x4;   // MFMA C/D frag
typedef __attribute__((ext_vector_type(8))) unsigned short us8;

static __device__ __forceinline__ unsigned short f2bf(float f) {
    union { float f; unsigned int u; } x; x.f = f;
    unsigned int r = x.u + 0x7FFFu + ((x.u >> 16) & 1u);   // RNE
    return (unsigned short)(r >> 16);
}
static __device__ __forceinline__ float bf2f(unsigned short u) {
    union { unsigned int u; float f; } x; x.u = ((unsigned int)u) << 16;
    return x.f;
}
static __device__ __forceinline__ void glds16(const void* g, void* l) {
    __builtin_amdgcn_global_load_lds(
        (const __attribute__((address_space(1))) void*)g,
        (__attribute__((address_space(3))) void*)l, 16, 0, 0);
}

// ---------------------------------------------------------------------------
// fp32 -> bf16 elementwise convert (n multiple of 8; grid = n/8/256)
// ---------------------------------------------------------------------------
__global__ __launch_bounds__(256) void cvt_bf16(const float* __restrict__ src,
                                                unsigned short* __restrict__ dst,
                                                long n)
{
    const long i = ((long)blockIdx.x * 256 + threadIdx.x) * 8;
    if (i >= n) return;
    const float4 v0 = *(const float4*)(src + i);
    const float4 v1 = *(const float4*)(src + i + 4);
    us8 o;
    o[0] = f2bf(v0.x); o[1] = f2bf(v0.y); o[2] = f2bf(v0.z); o[3] = f2bf(v0.w);
    o[4] = f2bf(v1.x); o[5] = f2bf(v1.y); o[6] = f2bf(v1.z); o[7] = f2bf(v1.w);
    *(us8*)(dst + i) = o;
}

// ---------------------------------------------------------------------------
// bf16 MFMA GEMM: C[m,n] = A[m,:] . Wt[n,:] + bias   (both K-contiguous)
// 128x128 tile, BK=32, 4 waves (2x2 of 64x64), 16x16x32 bf16 MFMA.
// mode 0: fp32 [M,N] out, bias0.
// mode 1: fused projection epilogue over N=5120 (Wqkv|Wk|Wv contiguous):
//   col <  3072 : bf16 qkv       -> out  (stride 3*D), bias0
//   col <  4096 : fp32 headsplit -> out2 seg 0 (k_col), bias1
//   col >= 4096 : fp32 headsplit -> out2 seg 1 (v_col), bias2
//   Region boundaries are 128-aligned, so branches are block-uniform.
// ---------------------------------------------------------------------------
__global__ __launch_bounds__(256) void gemm_bf16(
    const unsigned short* __restrict__ A,   // [M,K] bf16
    const unsigned short* __restrict__ Wt,  // [N,K] bf16
    const float* __restrict__ bias0,
    const float* __restrict__ bias1,
    const float* __restrict__ bias2,
    void* __restrict__ out,
    float* __restrict__ out2,
    int M, int N, int K, int mode)
{
    __shared__ __align__(16) unsigned short Asm[128 * 32];
    __shared__ __align__(16) unsigned short Bsm[128 * 32];

    const int t  = threadIdx.x;
    const int bm = blockIdx.y * 128;
    const int bn = blockIdx.x * 128;
    const int w = t >> 6, lane = t & 63;
    const int g = lane >> 4, c = lane & 15;
    const int wm = (w & 1) * 64, wn = (w >> 1) * 64;

    // staging: thread t -> slot t (issue 0) and slot 256+t (issue 1)
    const int r0  = t >> 2;                       // 0..63
    const int kc0 = (t & 3) ^ ((r0 >> 1) & 3);    // chunk swizzle
    const unsigned short* Ap0 = A  + (long)(bm + r0)      * K + kc0 * 8;
    const unsigned short* Ap1 = A  + (long)(bm + r0 + 64) * K + kc0 * 8;
    const unsigned short* Bp0 = Wt + (long)(bn + r0)      * K + kc0 * 8;
    const unsigned short* Bp1 = Wt + (long)(bn + r0 + 64) * K + kc0 * 8;
    unsigned short* AsD0 = Asm + t * 8;
    unsigned short* AsD1 = Asm + (256 + t) * 8;
    unsigned short* BsD0 = Bsm + t * 8;
    unsigned short* BsD1 = Bsm + (256 + t) * 8;

    // fragment LDS byte offsets
    const int xv = (c >> 1) & 3;
    int offA[4], offB[4];
#pragma unroll
    for (int i = 0; i < 4; i++) {
        offA[i] = (4 * (wm + i * 16 + c) + (g ^ xv)) * 16;
        offB[i] = (4 * (wn + i * 16 + c) + (g ^ xv)) * 16;
    }

    f32x4 acc[4][4];
#pragma unroll
    for (int i = 0; i < 4; i++)
#pragma unroll
        for (int j = 0; j < 4; j++) { acc[i][j][0]=0.f; acc[i][j][1]=0.f; acc[i][j][2]=0.f; acc[i][j][3]=0.f; }

    for (int k0 = 0; k0 < K; k0 += 32) {
        glds16(Ap0 + k0, AsD0);
        glds16(Ap1 + k0, AsD1);
        glds16(Bp0 + k0, BsD0);
        glds16(Bp1 + k0, BsD1);
        __syncthreads();                      // drains vmcnt -> LDS valid

        short8 af[4], bf[4];
#pragma unroll
        for (int i = 0; i < 4; i++) af[i] = *(const short8*)((const char*)Asm + offA[i]);
#pragma unroll
        for (int i = 0; i < 4; i++) bf[i] = *(const short8*)((const char*)Bsm + offB[i]);
#pragma unroll
        for (int mt = 0; mt < 4; mt++)
#pragma unroll
            for (int nt = 0; nt < 4; nt++)
                acc[mt][nt] = __builtin_amdgcn_mfma_f32_16x16x32_bf16(af[mt], bf[nt], acc[mt][nt], 0, 0, 0);
        __syncthreads();                      // protect LDS before next stage
    }

#pragma unroll
    for (int mt = 0; mt < 4; mt++) {
#pragma unroll
        for (int nt = 0; nt < 4; nt++) {
            const int col = bn + wn + nt * 16 + c;
            float bv;
            if (mode == 0)          bv = bias0[col];
            else if (col < 3 * D_)  bv = bias0[col];
            else if (col < 4 * D_)  bv = bias1[col - 3 * D_];
            else                    bv = bias2[col - 4 * D_];
            const int row0 = bm + wm + mt * 16 + g * 4;
#pragma unroll
            for (int reg = 0; reg < 4; reg++) {
                const float val = acc[mt][nt][reg] + bv;
                const int rr = row0 + reg;
                if (mode == 0) {
                    ((float*)out)[(long)rr * N + col] = val;
                } else if (col < 3 * D_) {
                    ((unsigned short*)out)[(long)rr * (3 * D_) + col] = f2bf(val);
                } else {
                    const int cc  = col - 3 * D_;
                    const int seg = cc >> 10;              // 0 = k_col, 1 = v_col
                    const int hh  = (cc >> 6) & 15;
                    const int d   = cc & 63;
                    const int b2 = rr >> 11, s2 = rr & 2047;
                    out2[(long)seg * ((long)B_ * H_ * S_ * DH_)
                         + (((long)(b2 * H_ + hh)) * S_ + s2) * DH_ + d] = val;
                }
            }
        }
    }
}

// ---------------------------------------------------------------------------
// Pre-pass (bf16 in): K -> packed [B,H,S,DH]; V -> transposed [B,H,DH,S].
// ---------------------------------------------------------------------------
__global__ __launch_bounds__(256) void prepass(const unsigned short* __restrict__ qkvb,
                                               unsigned short* __restrict__ Kb,
                                               unsigned short* __restrict__ Vtb)
{
    __shared__ __align__(16) unsigned short tile[64][72];
    const int bi = blockIdx.x;              // B*H*(S/64) = 1024
    const int st = bi & 31;
    const int bh = bi >> 5;
    const int b = bh >> 4, h = bh & 15;
    const int t = threadIdx.x;
    const int s_l = t >> 2;
    const int ch = (t & 3) * 16;            // 16 bf16 per thread

    const unsigned short* src = qkvb + (long)(b * S_ + st * 64 + s_l) * (3 * D_) + h * DH_;

    // K: straight copy into packed layout
    {
        us8 k0 = *(const us8*)(src + D_ + ch);
        us8 k1 = *(const us8*)(src + D_ + ch + 8);
        us8* kd = (us8*)(Kb + ((long)bh * S_ + st * 64 + s_l) * DH_ + ch);
        kd[0] = k0; kd[1] = k1;
    }
    // V: stage tile, transpose
    {
        us8 v0 = *(const us8*)(src + 2 * D_ + ch);
        us8 v1 = *(const us8*)(src + 2 * D_ + ch + 8);
        *(us8*)&tile[s_l][ch] = v0;
        *(us8*)&tile[s_l][ch + 8] = v1;
    }
    __syncthreads();
    {
        const int d_l = t >> 2;
        const int sch = (t & 3) * 16;
        us8 o0, o1;
#pragma unroll
        for (int i = 0; i < 8; i++) o0[i] = tile[sch + i][d_l];
#pragma unroll
        for (int i = 0; i < 8; i++) o1[i] = tile[sch + 8 + i][d_l];
        us8* dst = (us8*)(Vtb + ((long)bh * DH_ + d_l) * S_ + st * 64 + sch);
        dst[0] = o0; dst[1] = o1;
    }
}

// ---------------------------------------------------------------------------
// MFMA flash attention, round 4: uniform block duration.
//  - Each block processes TWO complementary Q-tiles sequentially:
//    qt = pair and qt = 63-pair. Tile counts sum to exactly 33 for every
//    pair -> all 1024 blocks have identical work, occupancy never decays,
//    the causal-tail (longest blocks finishing alone) is eliminated.
//    (r3 post-mortem: duration was tail-bound — occupancy fell 24->15% as
//    short blocks retired with no refill.)
//  - Keeps r3 machinery per phase: K register double-buffer (prefetch t+1
//    before computing t), V loaded at tile top, defer-max THR=8, per-lane
//    lsum, no barriers (wave-private LDS P-transpose + lgkmcnt fence).
// ---------------------------------------------------------------------------
#define LOAD_KTILE(K0, K1, TT) do {                                         \
    _Pragma("unroll")                                                       \
    for (int nt_ = 0; nt_ < 4; nt_++) {                                     \
        const unsigned short* kp_ = Kh + ((long)((TT) + nt_ * 16 + c)) * DH_ + g * 8; \
        K0[nt_] = *(const short8*)kp_;                                      \
        K1[nt_] = *(const short8*)(kp_ + 32);                               \
    }                                                                       \
} while (0)

#define ATTN_TILE(TT, K0, K1) do {                                          \
    const int t0_ = (TT);                                                   \
    short8 vv0_[4], vv1_[4];                                                \
    _Pragma("unroll")                                                       \
    for (int nt_ = 0; nt_ < 4; nt_++) {                                     \
        const unsigned short* vp_ = Vh + ((long)(nt_ * 16 + c)) * S_ + t0_ + g * 8; \
        vv0_[nt_] = *(const short8*)vp_;                                    \
        vv1_[nt_] = *(const short8*)(vp_ + 32);                             \
    }                                                                       \
    f32x4 sc_[4];                                                           \
    _Pragma("unroll")                                                       \
    for (int nt_ = 0; nt_ < 4; nt_++) {                                     \
        f32x4 a_; a_[0]=0.f; a_[1]=0.f; a_[2]=0.f; a_[3]=0.f;               \
        a_ = __builtin_amdgcn_mfma_f32_16x16x32_bf16(qa0, K0[nt_], a_, 0, 0, 0); \
        a_ = __builtin_amdgcn_mfma_f32_16x16x32_bf16(qa1, K1[nt_], a_, 0, 0, 0); \
        _Pragma("unroll")                                                   \
        for (int r_ = 0; r_ < 4; r_++) a_[r_] *= scale;                     \
        sc_[nt_] = a_;                                                      \
    }                                                                       \
    if (t0_ == tEnd) {                                                      \
        _Pragma("unroll")                                                   \
        for (int nt_ = 0; nt_ < 4; nt_++)                                   \
            _Pragma("unroll")                                               \
            for (int r_ = 0; r_ < 4; r_++)                                  \
                sc_[nt_][r_] = (nt_ * 16 + c > dr + g * 4 + r_) ? -INFINITY : sc_[nt_][r_]; \
    }                                                                       \
    float al_[4]; bool resc_ = false;                                       \
    _Pragma("unroll")                                                       \
    for (int r_ = 0; r_ < 4; r_++) {                                        \
        const float mx_ = fmaxf(fmaxf(sc_[0][r_], sc_[1][r_]),              \
                                fmaxf(sc_[2][r_], sc_[3][r_]));             \
        if (__all(mx_ <= m[r_] + 8.0f)) {                                   \
            al_[r_] = 1.0f;                                                 \
            float ps_ = 0.0f;                                               \
            _Pragma("unroll")                                               \
            for (int nt_ = 0; nt_ < 4; nt_++) {                             \
                const float p_ = __expf(sc_[nt_][r_] - m[r_]);              \
                sc_[nt_][r_] = p_; ps_ += p_;                               \
            }                                                               \
            lsum_l[r_] += ps_;                                              \
        } else {                                                            \
            resc_ = true;                                                   \
            float M_ = mx_;                                                 \
            M_ = fmaxf(M_, __shfl_xor(M_, 1));                              \
            M_ = fmaxf(M_, __shfl_xor(M_, 2));                              \
            M_ = fmaxf(M_, __shfl_xor(M_, 4));                              \
            M_ = fmaxf(M_, __shfl_xor(M_, 8));                              \
            const float mn_ = fmaxf(m[r_], M_);                             \
            const float a_ = __expf(m[r_] - mn_);                           \
            m[r_] = mn_; al_[r_] = a_;                                      \
            float ps_ = 0.0f;                                               \
            _Pragma("unroll")                                               \
            for (int nt_ = 0; nt_ < 4; nt_++) {                             \
                const float p_ = __expf(sc_[nt_][r_] - mn_);                \
                sc_[nt_][r_] = p_; ps_ += p_;                               \
            }                                                               \
            lsum_l[r_] = lsum_l[r_] * a_ + ps_;                             \
        }                                                                   \
    }                                                                       \
    if (resc_) {                                                            \
        _Pragma("unroll")                                                   \
        for (int f_ = 0; f_ < 4; f_++)                                      \
            _Pragma("unroll")                                               \
            for (int r_ = 0; r_ < 4; r_++)                                  \
                O[f_][r_] *= al_[r_];                                       \
    }                                                                       \
    _Pragma("unroll")                                                       \
    for (int nt_ = 0; nt_ < 4; nt_++)                                       \
        _Pragma("unroll")                                                   \
        for (int r_ = 0; r_ < 4; r_++)                                      \
            Pl[w][g * 4 + r_][nt_ * 16 + c] = f2bf(sc_[nt_][r_]);           \
    asm volatile("s_waitcnt lgkmcnt(0)" ::: "memory");                      \
    const short8 pa0_ = *(const short8*)&Pl[w][c][g * 8];                   \
    const short8 pa1_ = *(const short8*)&Pl[w][c][32 + g * 8];              \
    _Pragma("unroll")                                                       \
    for (int nt_ = 0; nt_ < 4; nt_++) {                                     \
        O[nt_] = __builtin_amdgcn_mfma_f32_16x16x32_bf16(pa0_, vv0_[nt_], O[nt_], 0, 0, 0); \
        O[nt_] = __builtin_amdgcn_mfma_f32_16x16x32_bf16(pa1_, vv1_[nt_], O[nt_], 0, 0, 0); \
    }                                                                       \
} while (0)

__global__ __launch_bounds__(128, 2) void attn_mfma(
    const unsigned short* __restrict__ qkvb,
    const unsigned short* __restrict__ Kb,
    const unsigned short* __restrict__ Vtb,
    const float* __restrict__ pk,
    const float* __restrict__ pv,
    unsigned short* __restrict__ ctxb)
{
    __shared__ float msc[2][16][8];
    __shared__ __align__(16) unsigned short Pl[2][16][72];

    const int bi   = blockIdx.x;
    const int bh   = bi >> 5;                // 0..31
    const int pair = bi & 31;                // 0..31 -> qt pair {pair, 63-pair}
    const int b = bh >> 4, h = bh & 15;
    const int w = threadIdx.x >> 6;          // 0..1, independent waves
    const int lane = threadIdx.x & 63;
    const int g = lane >> 4, c = lane & 15;
    const float scale = 0.125f;              // 1/sqrt(64); exact pow2

    const unsigned short* Kh = Kb + (long)bh * S_ * DH_;
    const unsigned short* Vh = Vtb + (long)bh * DH_ * S_;

#pragma unroll 1
    for (int ph = 0; ph < 2; ++ph) {
        const int qt    = ph ? (63 - pair) : pair;
        const int qrow0 = qt * 32 + w * 16;
        const int dr    = qrow0 & 63;        // row offset inside diagonal tile
        const int tEnd  = qrow0 & ~63;

        // Q A-frags straight from bf16 qkv (scale applied post-MFMA)
        const unsigned short* qp = qkvb + ((long)(b * S_) + qrow0 + c) * (3 * D_) + h * DH_;
        const short8 qa0 = *(const short8*)(qp + g * 8);
        const short8 qa1 = *(const short8*)(qp + 32 + g * 8);

        float m[4], lsum_l[4];
        f32x4 O[4];
#pragma unroll
        for (int f = 0; f < 4; f++) { O[f][0]=0.f; O[f][1]=0.f; O[f][2]=0.f; O[f][3]=0.f; }
#pragma unroll
        for (int reg = 0; reg < 4; reg++) { m[reg] = -INFINITY; lsum_l[reg] = 0.0f; }

        // register-pipelined main loop (K double-buffer, 2 tiles per trip)
        short8 kA0[4], kA1[4], kB0[4], kB1[4];
        LOAD_KTILE(kA0, kA1, 0);
        int t0 = 0;
        for (;;) {
            if (t0 + 64 <= tEnd) LOAD_KTILE(kB0, kB1, t0 + 64);
            ATTN_TILE(t0, kA0, kA1);
            if (t0 == tEnd) break;
            t0 += 64;
            if (t0 + 64 <= tEnd) LOAD_KTILE(kA0, kA1, t0 + 64);
            ATTN_TILE(t0, kB0, kB1);
            if (t0 == tEnd) break;
            t0 += 64;
        }

        // cross-lane lsum reduce (deferred from the main loop)
        float lsum[4];
#pragma unroll
        for (int reg = 0; reg < 4; reg++) {
            float s = lsum_l[reg];
            s += __shfl_xor(s, 1); s += __shfl_xor(s, 2);
            s += __shfl_xor(s, 4); s += __shfl_xor(s, 8);
            lsum[reg] = s;
        }

        // ---- depth-memory merge (fp32 pk/pv) + epilogue ----
        {
            const int r0 = lane >> 3, l0 = lane & 7;
#pragma unroll
            for (int pass = 0; pass < 2; pass++) {
                const int r = r0 + pass * 8;
                const unsigned short* qr = qkvb + ((long)(b * S_) + qrow0 + r) * (3 * D_) + h * DH_;
                const float4* k4 = (const float4*)(pk + (((long)bh * S_ + qrow0 + r) * L_ + l0) * DH_);
                float d = 0.0f;
#pragma unroll
                for (int i = 0; i < 8; i++) {
                    const us8 q8 = *(const us8*)(qr + i * 8);
                    const float4 ka = k4[2 * i], kb2 = k4[2 * i + 1];
                    d += bf2f(q8[0]) * ka.x  + bf2f(q8[1]) * ka.y
                       + bf2f(q8[2]) * ka.z  + bf2f(q8[3]) * ka.w
                       + bf2f(q8[4]) * kb2.x + bf2f(q8[5]) * kb2.y
                       + bf2f(q8[6]) * kb2.z + bf2f(q8[7]) * kb2.w;
                }
                msc[w][r][l0] = d * scale;
            }
        }
        asm volatile("s_waitcnt lgkmcnt(0)" ::: "memory");
#pragma unroll
        for (int reg = 0; reg < 4; reg++) {
            const int r = g * 4 + reg;
            float s8[8];
#pragma unroll
            for (int l = 0; l < 8; l++) s8[l] = msc[w][r][l];
            float mx = s8[0];
#pragma unroll
            for (int l = 1; l < 8; l++) mx = fmaxf(mx, s8[l]);
            const float mn = fmaxf(m[reg], mx);
            const float a  = __expf(m[reg] - mn);
            float p8[8]; float ls = 0.0f;
#pragma unroll
            for (int l = 0; l < 8; l++) { p8[l] = __expf(s8[l] - mn); ls += p8[l]; }
            const float rl = 1.0f / (lsum[reg] * a + ls);
            const float* pvr = pv + ((long)bh * S_ + qrow0 + r) * (L_ * DH_) + c;
            float acc4[4] = {0.f, 0.f, 0.f, 0.f};
#pragma unroll
            for (int l = 0; l < 8; l++)
#pragma unroll
                for (int f = 0; f < 4; f++)
                    acc4[f] += p8[l] * pvr[l * DH_ + f * 16];
            unsigned short* op = ctxb + ((long)(b * S_) + qrow0 + r) * D_ + h * DH_ + c;
#pragma unroll
            for (int f = 0; f < 4; f++)
                op[f * 16] = f2bf((O[f][reg] * a + acc4[f]) * rl);
        }
    }
}

// ---------------------------------------------------------------------------
extern "C" void kernel_launch(void* const* d_in, const int* in_sizes, int n_in,
                              void* d_out, int out_size, void* d_ws, size_t ws_size,
                              hipStream_t stream)
{
    const float* x    = (const float*)d_in[0];
    const float* pk   = (const float*)d_in[1];
    const float* pv   = (const float*)d_in[2];
    const float* Wqkv = (const float*)d_in[3];
    const float* bqkv = (const float*)d_in[4];
    const float* Wk   = (const float*)d_in[5];
    const float* bk   = (const float*)d_in[6];
    const float* Wv   = (const float*)d_in[7];
    const float* bv   = (const float*)d_in[8];
    const float* Wo   = (const float*)d_in[9];
    const float* bo   = (const float*)d_in[10];

    float* out   = (float*)d_out;                      // [B,S,D]
    float* k_col = out + (long)B_ * S_ * D_;           // [B,H,S,DH]
    // v_col = k_col + B*H*S*DH (seg 1 in fused gemm epilogue)

    const int M = B_ * S_;   // 4096
    const long MD = (long)M * D_;

    unsigned short* xb    = (unsigned short*)d_ws;     // [M,D]
    unsigned short* Wqkvb = xb + MD;                   // [3D,D]
    unsigned short* Wkb   = Wqkvb + 3L * D_ * D_;      // [D,D]  (contiguous after Wqkvb)
    unsigned short* Wvb   = Wkb + (long)D_ * D_;       // [D,D]  (contiguous after Wkb)
    unsigned short* Wob   = Wvb + (long)D_ * D_;
    unsigned short* qkvb  = Wob + (long)D_ * D_;       // [M,3D]
    unsigned short* Kb    = qkvb + 3 * MD;             // [B,H,S,DH]
    unsigned short* Vtb   = Kb + MD;                   // [B,H,DH,S]
    unsigned short* ctxb  = Vtb + MD;                  // [M,D]

    dim3 blk(256);

    // fp32 -> bf16 converts
    cvt_bf16<<<dim3((int)(MD / 2048)), blk, 0, stream>>>(x, xb, MD);
    cvt_bf16<<<dim3((int)(3L * D_ * D_ / 2048)), blk, 0, stream>>>(Wqkv, Wqkvb, 3L * D_ * D_);
    cvt_bf16<<<dim3((int)((long)D_ * D_ / 2048)), blk, 0, stream>>>(Wk, Wkb, (long)D_ * D_);
    cvt_bf16<<<dim3((int)((long)D_ * D_ / 2048)), blk, 0, stream>>>(Wv, Wvb, (long)D_ * D_);
    cvt_bf16<<<dim3((int)((long)D_ * D_ / 2048)), blk, 0, stream>>>(Wo, Wob, (long)D_ * D_);

    // 1) fused projections: qkv (bf16) + k_col/v_col (fp32 head-split)
    //    Wqkvb|Wkb|Wvb contiguous -> one [M,5120] GEMM, 1280 blocks
    gemm_bf16<<<dim3(5 * D_ / 128, M / 128), blk, 0, stream>>>(
        xb, Wqkvb, bqkv, bk, bv, qkvb, k_col, M, 5 * D_, D_, 1);
    // 2) packed bf16 K + transposed bf16 V
    prepass<<<dim3(B_ * H_ * (S_ / 64)), blk, 0, stream>>>(qkvb, Kb, Vtb);
    // 3) attention -> bf16 ctx (1024 uniform-duration blocks x 128 threads)
    attn_mfma<<<dim3(B_ * H_ * 32), dim3(128), 0, stream>>>(qkvb, Kb, Vtb, pk, pv, ctxb);
    // 4) out = ctx @ Wo.T + bo -> fp32
    gemm_bf16<<<dim3(D_ / 128, M / 128), blk, 0, stream>>>(
        ctxb, Wob, bo, nullptr, nullptr, out, nullptr, M, D_, D_, 0);
}